// Round 1
// baseline (360.693 us; speedup 1.0000x reference)
//
#include <hip/hip_runtime.h>

#define KC 32
#define DD 64
#define NB 65536          // batch
#define LOG2PI 1.8378770664093453f

typedef short short8 __attribute__((ext_vector_type(8)));
typedef float f32x4 __attribute__((ext_vector_type(4)));

__device__ __forceinline__ unsigned short f2bf(float f) {
    unsigned int u = __builtin_bit_cast(unsigned int, f);
    u = (u + 0x7FFFu + ((u >> 16) & 1u)) >> 16;   // RNE
    return (unsigned short)u;
}

__device__ __forceinline__ short8 pack8(float4 f0, float4 f1) {
    short8 r;
    r[0] = (short)f2bf(f0.x); r[1] = (short)f2bf(f0.y);
    r[2] = (short)f2bf(f0.z); r[3] = (short)f2bf(f0.w);
    r[4] = (short)f2bf(f1.x); r[5] = (short)f2bf(f1.y);
    r[6] = (short)f2bf(f1.z); r[7] = (short)f2bf(f1.w);
    return r;
}

// ---------------------------------------------------------------------------
// K1: per-component Cholesky, U = L^-1, logdet, v = U*c, W rows in bf16.
// 32 blocks (one per k) x 64 threads (one wave).
// ---------------------------------------------------------------------------
__global__ __launch_bounds__(64) void prep_kernel(
    const float* __restrict__ cov, const float* __restrict__ centroid,
    unsigned short* __restrict__ wW, float* __restrict__ wV,
    float* __restrict__ wC, float* __restrict__ wAcc)
{
    __shared__ float A[64 * 65];     // cov -> L (lower, in place)
    __shared__ float Ui[64 * 65];    // L^-1
    __shared__ float dinv[64];
    __shared__ float cs[64];
    const int k = blockIdx.x;
    const int t = threadIdx.x;       // 0..63

    for (int it = 0; it < 64; ++it) {
        int idx = it * 64 + t;
        A[(idx >> 6) * 65 + (idx & 63)] = cov[k * 4096 + idx];
    }
    cs[t] = centroid[k * 64 + t];
    if (k == 0 && t == 0) wAcc[0] = 0.0f;   // ws is re-poisoned each launch
    __syncthreads();

    // Cholesky (right-looking, lower triangle only)
    for (int j = 0; j < 64; ++j) {
        float piv = A[j * 65 + j];
        float r = rsqrtf(piv);
        if (t > j)  A[t * 65 + j] *= r;
        if (t == j) A[j * 65 + j] = piv * r;   // sqrt(piv)
        __syncthreads();
        float lij = (t > j) ? A[t * 65 + j] : 0.0f;
        for (int p = j + 1; p <= t; ++p)
            A[t * 65 + p] -= lij * A[p * 65 + j];
        __syncthreads();
    }

    // logdet + diag reciprocals
    float dg = A[t * 65 + t];
    dinv[t] = 1.0f / dg;
    float lg = logf(dg);
    for (int off = 32; off > 0; off >>= 1) lg += __shfl_down(lg, off);
    if (t == 0) wC[k] = 64.0f * LOG2PI + 2.0f * lg;
    __syncthreads();

    // U = L^-1: lane t owns column c=t (column solve is lane-private)
    const int c = t;
    for (int i = 0; i < 64; ++i) {
        float s = (i == c) ? 1.0f : 0.0f;
        for (int j = 0; j < i; ++j)
            s -= A[i * 65 + j] * Ui[j * 65 + c];
        Ui[i * 65 + c] = s * dinv[i];
    }
    __syncthreads();

    // v_d = sum_e U[d][e]*c[e]  (lane d)
    {
        float s = 0.0f;
        for (int e = 0; e <= t; ++e) s += Ui[t * 65 + e] * cs[e];
        wV[k * 64 + t] = s;
    }
    // W rows (bf16): Wt[k*64+d][e] = U[d][e]; lane t = e (coalesced stores)
    for (int d = 0; d < 64; ++d)
        wW[(k * 64 + d) * 64 + t] = f2bf(Ui[d * 65 + t]);
}

// ---------------------------------------------------------------------------
// K2: fused gather + GEMM (Z = X W^T via mfma 16x16x32 bf16) + squared-norm
//     epilogue weighted by resp, block-reduced to one atomicAdd.
// Grid: 1024 = 256 row-blocks (256 b each) x 4 N-quarters (512 n = 8 k's).
// Block: 256 thr = 4 waves, wave handles 64 rows x its whole quarter.
// ---------------------------------------------------------------------------
__global__ __launch_bounds__(256) void main_kernel(
    const float* __restrict__ emb, const float* __restrict__ pi,
    const int* __restrict__ labels, const unsigned short* __restrict__ wW,
    const float* __restrict__ wV, const float* __restrict__ wC,
    float* __restrict__ wAcc)
{
    __shared__ int   lab[256];
    __shared__ float Rg[256 * 12];   // resp tile, stride 12 (aligned + bank-spread)
    __shared__ float vq[512];
    __shared__ float cdet[8];
    __shared__ float red[4];

    const int tid = threadIdx.x;
    const int bid = blockIdx.x;
    const int rb = bid & 255;        // row-block
    const int q4 = bid >> 8;         // N-quarter 0..3
    const int row0 = rb * 256;
    const int n0 = q4 * 512;

    lab[tid] = labels[row0 + tid];
    vq[tid] = wV[n0 + tid];
    vq[256 + tid] = wV[n0 + 256 + tid];
    if (tid < 8) cdet[tid] = wC[q4 * 8 + tid];
    __syncthreads();

    // stage resp tile: rows row0..row0+255, k's q4*8..q4*8+7
    {
        const float4* pi4 = (const float4*)pi;
        for (int it = 0; it < 2; ++it) {
            int id = it * 256 + tid;
            int r = id >> 1, h = id & 1;
            float4 f = pi4[(size_t)lab[r] * 8 + q4 * 2 + h];
            *(float4*)&Rg[r * 12 + h * 4] = f;
        }
    }

    const int w  = tid >> 6;   // wave 0..3
    const int l  = tid & 63;
    const int m  = l & 15;     // A row within tile / B col / C col
    const int qd = l >> 4;     // quad

    // A fragments: 4 row-tiles x 2 k-steps, gathered from embedding, fp32->bf16
    short8 afr[4][2];
    {
        const float4* emb4 = (const float4*)emb;
        for (int rt = 0; rt < 4; ++rt) {
            int lb = lab[w * 64 + rt * 16 + m];
            size_t base = (size_t)lb * 16 + qd * 2;
            for (int s = 0; s < 2; ++s) {
                float4 f0 = emb4[base + s * 8];
                float4 f1 = emb4[base + s * 8 + 1];
                afr[rt][s] = pack8(f0, f1);
            }
        }
    }
    __syncthreads();   // Rg ready

    float qa[4][4] = {};
    float part = 0.0f;
    const uint4* w4 = (const uint4*)wW;

    for (int nt = 0; nt < 32; ++nt) {
        int nloc = nt * 16 + m;
        int row = n0 + nloc;
        short8 b0 = __builtin_bit_cast(short8, w4[row * 8 + qd]);
        short8 b1 = __builtin_bit_cast(short8, w4[row * 8 + 4 + qd]);
        float vv = vq[nloc];
#pragma unroll
        for (int rt = 0; rt < 4; ++rt) {
            f32x4 cc = {0.0f, 0.0f, 0.0f, 0.0f};
            cc = __builtin_amdgcn_mfma_f32_16x16x32_bf16(afr[rt][0], b0, cc, 0, 0, 0);
            cc = __builtin_amdgcn_mfma_f32_16x16x32_bf16(afr[rt][1], b1, cc, 0, 0, 0);
#pragma unroll
            for (int r2 = 0; r2 < 4; ++r2) {
                float z = cc[r2] - vv;
                qa[rt][r2] = fmaf(z, z, qa[rt][r2]);
            }
        }
        if ((nt & 3) == 3) {               // k complete (its 4 n-tiles done)
            int kloc = nt >> 2;
            float cd = cdet[kloc] * 0.0625f;   // /16: 16 lanes share each (b,k)
#pragma unroll
            for (int rt = 0; rt < 4; ++rt) {
#pragma unroll
                for (int r2 = 0; r2 < 4; ++r2) {
                    int rowl = w * 64 + rt * 16 + qd * 4 + r2;
                    part = fmaf(Rg[rowl * 12 + kloc], qa[rt][r2] + cd, part);
                    qa[rt][r2] = 0.0f;
                }
            }
        }
    }

    for (int off = 32; off > 0; off >>= 1) part += __shfl_down(part, off);
    if (l == 0) red[w] = part;
    __syncthreads();
    if (tid == 0) atomicAdd(wAcc, red[0] + red[1] + red[2] + red[3]);
}

__global__ void fin_kernel(const float* __restrict__ wAcc, float* __restrict__ out) {
    out[0] = fabsf(0.5f * wAcc[0]);
}

extern "C" void kernel_launch(void* const* d_in, const int* in_sizes, int n_in,
                              void* d_out, int out_size, void* d_ws, size_t ws_size,
                              hipStream_t stream) {
    const float* emb    = (const float*)d_in[0];
    const float* cent   = (const float*)d_in[1];
    const float* cov    = (const float*)d_in[2];
    const float* pi     = (const float*)d_in[3];
    const int*   labels = (const int*)d_in[4];
    float* out = (float*)d_out;

    char* w = (char*)d_ws;
    unsigned short* wW = (unsigned short*)w;              // 2048*64 bf16 = 262144 B
    float* wV  = (float*)(w + 262144);                    // 2048 f32   = 8192 B
    float* wC  = (float*)(w + 270336);                    // 32 f32
    float* wAcc = (float*)(w + 270464);                   // 1 f32

    prep_kernel<<<32, 64, 0, stream>>>(cov, cent, wW, wV, wC, wAcc);
    main_kernel<<<1024, 256, 0, stream>>>(emb, pi, labels, wW, wV, wC, wAcc);
    fin_kernel<<<1, 1, 0, stream>>>(wAcc, out);
}